// Round 3
// baseline (901.690 us; speedup 1.0000x reference)
//
#include <hip/hip_runtime.h>
#include <hip/hip_bf16.h>

typedef short s16x8 __attribute__((ext_vector_type(8)));
typedef float f32x4 __attribute__((ext_vector_type(4)));
typedef unsigned short us8 __attribute__((ext_vector_type(8)));
typedef unsigned short us4 __attribute__((ext_vector_type(4)));

#define T_TOK 8192
#define DDIM 1024
#define NEXP 8
#define FDIM 4096
#define MAXT256 72
#define MAXT128 136
#define PADMAX (16384 + NEXP * 256)

#define GLOAD16(dst, src) \
  __builtin_amdgcn_global_load_lds((const __attribute__((address_space(1))) unsigned int*)(src), \
                                   (__attribute__((address_space(3))) unsigned int*)(dst), 16, 0, 0)
#define WAITVM(n) asm volatile("s_waitcnt vmcnt(" #n ")" ::: "memory")
#define MEMFENCE asm volatile("" ::: "memory")

__device__ __forceinline__ float gelu_fast(float x) {
  // 0.5*x*(1+tanh(u)), tanh via exp identity (v_exp_f32), exact rewrite
  float u = 0.7978845608028654f * x * (1.0f + 0.044715f * x * x);
  float t = __expf(-2.0f * fabsf(u));
  float th = (1.0f - t) / (1.0f + t);
  th = u >= 0.f ? th : -th;
  return 0.5f * x * (1.0f + th);
}
__device__ __forceinline__ float bf2f(unsigned short v) {
  return __uint_as_float((unsigned)v << 16);
}

// ---------------- gating ----------------
__global__ __launch_bounds__(256) void gate_kernel(
    const float* __restrict__ x, const float* __restrict__ gw,
    int* __restrict__ counts, int* __restrict__ tok_e, float* __restrict__ tok_w)
{
  int lane = threadIdx.x & 63;
  int tok = blockIdx.x * 4 + (threadIdx.x >> 6);
  const float* xr = x + (size_t)tok * DDIM;
  float acc[NEXP];
#pragma unroll
  for (int e = 0; e < NEXP; ++e) acc[e] = 0.f;
  for (int i = 0; i < DDIM / 64; ++i) {
    int d = i * 64 + lane;
    float xv = xr[d];
    const float* g = gw + (size_t)d * NEXP;
#pragma unroll
    for (int e = 0; e < NEXP; ++e) acc[e] += xv * g[e];
  }
#pragma unroll
  for (int off = 32; off > 0; off >>= 1) {
#pragma unroll
    for (int e = 0; e < NEXP; ++e) acc[e] += __shfl_xor(acc[e], off);
  }
  if (lane == 0) {
    int i1 = 0; float m1 = acc[0];
#pragma unroll
    for (int e = 1; e < NEXP; ++e) if (acc[e] > m1) { m1 = acc[e]; i1 = e; }
    int i2 = -1; float m2 = -3.4e38f;
#pragma unroll
    for (int e = 0; e < NEXP; ++e) if (e != i1 && acc[e] > m2) { m2 = acc[e]; i2 = e; }
    float w1 = 1.f / (1.f + expf(m2 - m1));
    tok_e[tok * 2] = i1; tok_e[tok * 2 + 1] = i2;
    tok_w[tok * 2] = w1; tok_w[tok * 2 + 1] = 1.f - w1;
    atomicAdd(&counts[i1], 1);
    atomicAdd(&counts[i2], 1);
  }
}

// ---------------- scan: pad to 256, build 256- and 128-row tile tables ----------------
__global__ void scan_kernel(const int* __restrict__ counts, int* padded_off,
                            int* t256_e, int* t256_row, int* n256,
                            int* t128_e, int* t128_row, int* n128)
{
  if (threadIdx.x == 0 && blockIdx.x == 0) {
    int off = 0, a = 0, b = 0;
    for (int e = 0; e < NEXP; ++e) {
      padded_off[e] = off;
      int c = counts[e];
      int nt2 = (c + 255) / 256;
      int nt1 = (c + 127) / 128;
      for (int i = 0; i < nt2; ++i) { t256_e[a] = e; t256_row[a] = off + i * 256; ++a; }
      for (int i = 0; i < nt1; ++i) { t128_e[b] = e; t128_row[b] = off + i * 128; ++b; }
      off += nt2 * 256;
    }
    *n256 = a; *n128 = b;
  }
}

__global__ void init_pairs(int* __restrict__ pair_token) {
  int i = blockIdx.x * 256 + threadIdx.x;
  if (i < PADMAX) pair_token[i] = -1;
}

__global__ void scatter_kernel(const int* __restrict__ tok_e,
                               const int* __restrict__ padded_off, int* __restrict__ fill,
                               int* __restrict__ pair_token, int* __restrict__ tok_slot)
{
  int tok = blockIdx.x * 256 + threadIdx.x;
  if (tok >= T_TOK) return;
#pragma unroll
  for (int k = 0; k < 2; ++k) {
    int e = tok_e[tok * 2 + k];
    int slot = padded_off[e] + atomicAdd(&fill[e], 1);
    pair_token[slot] = tok;
    tok_slot[tok * 2 + k] = slot;
  }
}

// ---------------- gather tokens -> bf16 rows (zeros for padding) ----------------
__global__ __launch_bounds__(256) void gather_x(
    const float* __restrict__ x, const int* __restrict__ pair_token,
    __hip_bfloat16* __restrict__ Xg)
{
  int gid = blockIdx.x * 256 + threadIdx.x;
  int r = gid >> 7;
  int c = (gid & 127) << 3;
  if (r >= PADMAX) return;
  int tk = pair_token[r];
  __hip_bfloat16 v[8];
  if (tk < 0) {
#pragma unroll
    for (int j = 0; j < 8; ++j) v[j] = __float2bfloat16(0.f);
  } else {
    const float* src = x + (size_t)tk * DDIM + c;
#pragma unroll
    for (int j = 0; j < 8; ++j) v[j] = __float2bfloat16(src[j]);
  }
  *(us8*)(Xg + (size_t)r * DDIM + c) = *(const us8*)v;
}

// ------- fp32 (R,C) -> bf16 (C,R) transpose+convert, per expert z -------
__global__ __launch_bounds__(256) void transpose_conv(
    const float* __restrict__ in, __hip_bfloat16* __restrict__ out, int R, int C)
{
  __shared__ __hip_bfloat16 tile[64][68];
  size_t mat = (size_t)R * C;
  const float* ip = in + (size_t)blockIdx.z * mat;
  __hip_bfloat16* op = out + (size_t)blockIdx.z * mat;
  int c0 = blockIdx.x * 64, r0 = blockIdx.y * 64;
  int tx = threadIdx.x & 31, ty = threadIdx.x >> 5;
#pragma unroll
  for (int i = 0; i < 8; ++i) {
    int r = r0 + ty + i * 8;
    float2 v = *(const float2*)(ip + (size_t)r * C + c0 + tx * 2);
    tile[ty + i * 8][tx * 2]     = __float2bfloat16(v.x);
    tile[ty + i * 8][tx * 2 + 1] = __float2bfloat16(v.y);
  }
  __syncthreads();
#pragma unroll
  for (int i = 0; i < 8; ++i) {
    int cc = c0 + ty + i * 8;
    __hip_bfloat16 a = tile[tx * 2][ty + i * 8];
    __hip_bfloat16 b = tile[tx * 2 + 1][ty + i * 8];
    unsigned short ua = *(unsigned short*)&a, ub = *(unsigned short*)&b;
    unsigned int packed = (unsigned)ua | ((unsigned)ub << 16);
    *(unsigned int*)(op + (size_t)cc * R + r0 + tx * 2) = packed;
  }
}

// ---------------- pipelined grouped GEMM (counted-vmcnt double buffer) ----------------
// TM x 256 tile, BK=64, 8 waves (2M x 4N), per-wave (TM/2) x 64 output.
template<int TM, int LDA, int LDB, int NT, int LDO, bool GELU>
__global__ __launch_bounds__(512, 2) void moe_gemm(
    const __hip_bfloat16* __restrict__ Abase,
    const __hip_bfloat16* __restrict__ Bbase,
    __hip_bfloat16* __restrict__ Out,
    const int* __restrict__ tile_e, const int* __restrict__ tile_row,
    const int* __restrict__ numTiles)
{
  constexpr int MFR = TM / 32;      // A-fragments per wave (8 or 4)
  constexpr int AI  = TM / 64;      // A staging instrs per thread (4 or 2)
  constexpr int LPT = AI + 4;       // loads per tile per thread (8 or 6)
  constexpr int WR  = TM / 2;       // rows per wave
  if ((int)blockIdx.x >= *numTiles) return;
  __shared__ __align__(16) __hip_bfloat16 aS[2][TM * 64];
  __shared__ __align__(16) __hip_bfloat16 bS[2][256 * 64];
  int e = tile_e[blockIdx.x];
  int row0 = tile_row[blockIdx.x];
  int col0 = blockIdx.y * 256;
  int t = threadIdx.x, lane = t & 63, wid = t >> 6;
  int wm = wid >> 2, wn = wid & 3;
  int fr = lane & 15, fkg = lane >> 4;
  const __hip_bfloat16* Ab = Abase + (size_t)row0 * LDA;
  const __hip_bfloat16* Bb = Bbase + (size_t)e * (FDIM * DDIM) + (size_t)col0 * LDB;
  // staging: thread covers row (i*64 + t>>3), 16B granule (t&7), source pre-swizzled
  int srow = t >> 3;
  int gx = ((t & 7) ^ (srow & 7)) * 8;
  const __hip_bfloat16* aP = Ab + (size_t)srow * LDA + gx;
  const __hip_bfloat16* bP = Bb + (size_t)srow * LDB + gx;
  f32x4 acc[MFR][4] = {};

  auto STAGE = [&](int buf, int kt) {
#pragma unroll
    for (int i = 0; i < AI; ++i)
      GLOAD16(&aS[buf][wid * 512 + i * 4096], aP + (size_t)(i * 64) * LDA + kt * 64);
#pragma unroll
    for (int i = 0; i < 4; ++i)
      GLOAD16(&bS[buf][wid * 512 + i * 4096], bP + (size_t)(i * 64) * LDB + kt * 64);
  };

  STAGE(0, 0);
  STAGE(1, 1);
  for (int kt = 0; kt < NT; ++kt) {
    int buf = kt & 1;
    if (kt + 1 < NT) {
      if constexpr (LPT == 8) WAITVM(8); else WAITVM(6);
    } else {
      WAITVM(0);
    }
    __builtin_amdgcn_s_barrier();
    MEMFENCE;
    const __hip_bfloat16* aT = &aS[buf][0];
    const __hip_bfloat16* bT = &bS[buf][0];
#pragma unroll
    for (int kk = 0; kk < 2; ++kk) {
      int sw = (((kk << 2) | fkg) ^ (fr & 7)) * 8;
      int abase = (wm * WR + fr) * 64 + sw;
      int bbase = (wn * 64 + fr) * 64 + sw;
      s16x8 af[MFR], bfv[4];
#pragma unroll
      for (int m = 0; m < MFR; ++m) af[m] = *(const s16x8*)(aT + abase + m * 1024);
#pragma unroll
      for (int n = 0; n < 4; ++n) bfv[n] = *(const s16x8*)(bT + bbase + n * 1024);
      __builtin_amdgcn_s_setprio(1);
#pragma unroll
      for (int m = 0; m < MFR; ++m)
#pragma unroll
        for (int n = 0; n < 4; ++n)
          acc[m][n] = __builtin_amdgcn_mfma_f32_16x16x32_bf16(af[m], bfv[n], acc[m][n], 0, 0, 0);
      __builtin_amdgcn_s_setprio(0);
    }
    MEMFENCE;
    __builtin_amdgcn_s_barrier();
    MEMFENCE;
    if (kt + 2 < NT) STAGE(buf, kt + 2);
  }

  int orow = fkg * 4;
#pragma unroll
  for (int m = 0; m < MFR; ++m) {
    int r = row0 + wm * WR + m * 16 + orow;
#pragma unroll
    for (int j = 0; j < 4; ++j) {
#pragma unroll
      for (int n = 0; n < 4; ++n) {
        int c = col0 + wn * 64 + n * 16 + fr;
        float v = acc[m][n][j];
        if (GELU) v = gelu_fast(v);
        Out[(size_t)(r + j) * LDO + c] = __float2bfloat16(v);
      }
    }
  }
}

// ---------------- combine: out[tok] = wa*Eout[sa] + wb*Eout[sb] ----------------
__global__ __launch_bounds__(256) void combine_kernel(
    const __hip_bfloat16* __restrict__ Eout, const int* __restrict__ tok_slot,
    const float* __restrict__ tok_w, float* __restrict__ out)
{
  int tok = blockIdx.x;
  int sa = tok_slot[tok * 2], sb = tok_slot[tok * 2 + 1];
  float wa = tok_w[tok * 2], wb = tok_w[tok * 2 + 1];
  const __hip_bfloat16* ra = Eout + (size_t)sa * DDIM;
  const __hip_bfloat16* rb = Eout + (size_t)sb * DDIM;
  float* op = out + (size_t)tok * DDIM;
  int c = threadIdx.x * 4;
  us4 va = *(const us4*)(ra + c);
  us4 vb = *(const us4*)(rb + c);
  float4 o;
  o.x = wa * bf2f(va.x) + wb * bf2f(vb.x);
  o.y = wa * bf2f(va.y) + wb * bf2f(vb.y);
  o.z = wa * bf2f(va.z) + wb * bf2f(vb.z);
  o.w = wa * bf2f(va.w) + wb * bf2f(vb.w);
  *(float4*)(op + c) = o;
}

extern "C" void kernel_launch(void* const* d_in, const int* in_sizes, int n_in,
                              void* d_out, int out_size, void* d_ws, size_t ws_size,
                              hipStream_t stream)
{
  const float* x      = (const float*)d_in[0];
  const float* gate_w = (const float*)d_in[1];
  const float* w1     = (const float*)d_in[2];
  const float* w2     = (const float*)d_in[3];
  float* out = (float*)d_out;

  char* ws = (char*)d_ws;
  size_t off = 0;
  auto alloc = [&](size_t bytes) -> void* {
    void* p = ws + off;
    off = (off + bytes + 255) & ~(size_t)255;
    return p;
  };
  int*   counts     = (int*)alloc(NEXP * 4);      // first 1 KiB = control block
  int*   fill       = (int*)alloc(NEXP * 4);
  int*   padded_off = (int*)alloc(NEXP * 4);
  int*   n256       = (int*)alloc(4);
  int*   n128       = (int*)alloc(4);
  int*   t256_e     = (int*)alloc(MAXT256 * 4);
  int*   t256_row   = (int*)alloc(MAXT256 * 4);
  int*   t128_e     = (int*)alloc(MAXT128 * 4);
  int*   t128_row   = (int*)alloc(MAXT128 * 4);
  int*   tok_e      = (int*)alloc((size_t)T_TOK * 2 * 4);
  float* tok_w      = (float*)alloc((size_t)T_TOK * 2 * 4);
  int*   tok_slot   = (int*)alloc((size_t)T_TOK * 2 * 4);
  int*   pair_token = (int*)alloc((size_t)PADMAX * 4);
  __hip_bfloat16* XgEout = (__hip_bfloat16*)alloc((size_t)PADMAX * DDIM * 2); // Xg, later Eout
  __hip_bfloat16* W1t  = (__hip_bfloat16*)alloc((size_t)NEXP * FDIM * DDIM * 2);
  __hip_bfloat16* W2t  = (__hip_bfloat16*)alloc((size_t)NEXP * FDIM * DDIM * 2);
  __hip_bfloat16* Hbuf = (__hip_bfloat16*)alloc((size_t)PADMAX * FDIM * 2);
  (void)in_sizes; (void)n_in; (void)ws_size; (void)out_size;

  hipMemsetAsync(d_ws, 0, 1024, stream);

  transpose_conv<<<dim3(FDIM / 64, DDIM / 64, NEXP), 256, 0, stream>>>(w1, W1t, DDIM, FDIM);
  transpose_conv<<<dim3(DDIM / 64, FDIM / 64, NEXP), 256, 0, stream>>>(w2, W2t, FDIM, DDIM);

  gate_kernel<<<T_TOK / 4, 256, 0, stream>>>(x, gate_w, counts, tok_e, tok_w);
  scan_kernel<<<1, 64, 0, stream>>>(counts, padded_off, t256_e, t256_row, n256,
                                    t128_e, t128_row, n128);
  init_pairs<<<(PADMAX + 255) / 256, 256, 0, stream>>>(pair_token);
  scatter_kernel<<<T_TOK / 256, 256, 0, stream>>>(tok_e, padded_off, fill,
                                                  pair_token, tok_slot);
  gather_x<<<(PADMAX * (DDIM / 8) + 255) / 256, 256, 0, stream>>>(x, pair_token, XgEout);

  // ffn1: H = gelu(Xg @ W1t[e]^T)   (M=padded rows, N=4096, K=1024)
  moe_gemm<256, DDIM, DDIM, DDIM / 64, FDIM, true>
      <<<dim3(MAXT256, FDIM / 256), 512, 0, stream>>>(XgEout, W1t, Hbuf,
                                                      t256_e, t256_row, n256);
  // ffn2: Eout = H @ W2t[e]^T       (M=padded rows, N=1024, K=4096)
  moe_gemm<128, FDIM, FDIM, FDIM / 64, DDIM, false>
      <<<dim3(MAXT128, DDIM / 256), 512, 0, stream>>>(Hbuf, W2t, XgEout,
                                                      t128_e, t128_row, n128);

  combine_kernel<<<T_TOK, 256, 0, stream>>>(XgEout, tok_slot, tok_w, out);
}

// Round 4
// 814.677 us; speedup vs baseline: 1.1068x; 1.1068x over previous
//
#include <hip/hip_runtime.h>
#include <hip/hip_bf16.h>

typedef short s16x8 __attribute__((ext_vector_type(8)));
typedef float f32x4 __attribute__((ext_vector_type(4)));
typedef unsigned short us8 __attribute__((ext_vector_type(8)));
typedef unsigned short us4 __attribute__((ext_vector_type(4)));

#define T_TOK 8192
#define DDIM 1024
#define NEXP 8
#define FDIM 4096
#define MAXT 72
#define PADMAX (16384 + NEXP * 256)

#define GLOAD16(dst, src) \
  __builtin_amdgcn_global_load_lds((const __attribute__((address_space(1))) unsigned int*)(src), \
                                   (__attribute__((address_space(3))) unsigned int*)(dst), 16, 0, 0)
#define WAITVM(n) asm volatile("s_waitcnt vmcnt(" #n ")" ::: "memory")
#define MEMFENCE asm volatile("" ::: "memory")

__device__ __forceinline__ float gelu_fast(float x) {
  float u = 0.7978845608028654f * x * (1.0f + 0.044715f * x * x);
  float t = __expf(-2.0f * fabsf(u));
  float th = (1.0f - t) / (1.0f + t);
  th = u >= 0.f ? th : -th;
  return 0.5f * x * (1.0f + th);
}
__device__ __forceinline__ float bf2f(unsigned short v) {
  return __uint_as_float((unsigned)v << 16);
}

// ---------------- gating ----------------
__global__ __launch_bounds__(256) void gate_kernel(
    const float* __restrict__ x, const float* __restrict__ gw,
    int* __restrict__ counts, int* __restrict__ tok_e, float* __restrict__ tok_w)
{
  int lane = threadIdx.x & 63;
  int tok = blockIdx.x * 4 + (threadIdx.x >> 6);
  const float* xr = x + (size_t)tok * DDIM;
  float acc[NEXP];
#pragma unroll
  for (int e = 0; e < NEXP; ++e) acc[e] = 0.f;
  for (int i = 0; i < DDIM / 64; ++i) {
    int d = i * 64 + lane;
    float xv = xr[d];
    const float* g = gw + (size_t)d * NEXP;
#pragma unroll
    for (int e = 0; e < NEXP; ++e) acc[e] += xv * g[e];
  }
#pragma unroll
  for (int off = 32; off > 0; off >>= 1) {
#pragma unroll
    for (int e = 0; e < NEXP; ++e) acc[e] += __shfl_xor(acc[e], off);
  }
  if (lane == 0) {
    int i1 = 0; float m1 = acc[0];
#pragma unroll
    for (int e = 1; e < NEXP; ++e) if (acc[e] > m1) { m1 = acc[e]; i1 = e; }
    int i2 = -1; float m2 = -3.4e38f;
#pragma unroll
    for (int e = 0; e < NEXP; ++e) if (e != i1 && acc[e] > m2) { m2 = acc[e]; i2 = e; }
    float w1 = 1.f / (1.f + expf(m2 - m1));
    tok_e[tok * 2] = i1; tok_e[tok * 2 + 1] = i2;
    tok_w[tok * 2] = w1; tok_w[tok * 2 + 1] = 1.f - w1;
    atomicAdd(&counts[i1], 1);
    atomicAdd(&counts[i2], 1);
  }
}

// ---------------- scan: pad to 256, tile table ----------------
__global__ void scan_kernel(const int* __restrict__ counts, int* padded_off,
                            int* tile_e, int* tile_row, int* numTiles)
{
  if (threadIdx.x == 0 && blockIdx.x == 0) {
    int off = 0, a = 0;
    for (int e = 0; e < NEXP; ++e) {
      padded_off[e] = off;
      int c = counts[e];
      int nt = (c + 255) / 256;
      for (int i = 0; i < nt; ++i) { tile_e[a] = e; tile_row[a] = off + i * 256; ++a; }
      off += nt * 256;
    }
    *numTiles = a;
  }
}

__global__ void init_pairs(int* __restrict__ pair_token) {
  int i = blockIdx.x * 256 + threadIdx.x;
  if (i < PADMAX) pair_token[i] = -1;
}

__global__ void scatter_kernel(const int* __restrict__ tok_e,
                               const int* __restrict__ padded_off, int* __restrict__ fill,
                               int* __restrict__ pair_token, int* __restrict__ tok_slot)
{
  int tok = blockIdx.x * 256 + threadIdx.x;
  if (tok >= T_TOK) return;
#pragma unroll
  for (int k = 0; k < 2; ++k) {
    int e = tok_e[tok * 2 + k];
    int slot = padded_off[e] + atomicAdd(&fill[e], 1);
    pair_token[slot] = tok;
    tok_slot[tok * 2 + k] = slot;
  }
}

// ---------------- gather tokens -> bf16 rows (zeros for padding) ----------------
__global__ __launch_bounds__(256) void gather_x(
    const float* __restrict__ x, const int* __restrict__ pair_token,
    __hip_bfloat16* __restrict__ Xg)
{
  int gid = blockIdx.x * 256 + threadIdx.x;
  int r = gid >> 7;
  int c = (gid & 127) << 3;
  if (r >= PADMAX) return;
  int tk = pair_token[r];
  __hip_bfloat16 v[8];
  if (tk < 0) {
#pragma unroll
    for (int j = 0; j < 8; ++j) v[j] = __float2bfloat16(0.f);
  } else {
    const float* src = x + (size_t)tk * DDIM + c;
#pragma unroll
    for (int j = 0; j < 8; ++j) v[j] = __float2bfloat16(src[j]);
  }
  *(us8*)(Xg + (size_t)r * DDIM + c) = *(const us8*)v;
}

// ------- fp32 (R,C) -> bf16 (C,R) transpose+convert, per expert z -------
__global__ __launch_bounds__(256) void transpose_conv(
    const float* __restrict__ in, __hip_bfloat16* __restrict__ out, int R, int C)
{
  __shared__ __hip_bfloat16 tile[64][66];   // stride 33 dwords -> conflict-free
  size_t mat = (size_t)R * C;
  const float* ip = in + (size_t)blockIdx.z * mat;
  __hip_bfloat16* op = out + (size_t)blockIdx.z * mat;
  int c0 = blockIdx.x * 64, r0 = blockIdx.y * 64;
  int tx = threadIdx.x & 31, ty = threadIdx.x >> 5;
#pragma unroll
  for (int i = 0; i < 8; ++i) {
    int r = r0 + ty + i * 8;
    float2 v = *(const float2*)(ip + (size_t)r * C + c0 + tx * 2);
    tile[ty + i * 8][tx * 2]     = __float2bfloat16(v.x);
    tile[ty + i * 8][tx * 2 + 1] = __float2bfloat16(v.y);
  }
  __syncthreads();
#pragma unroll
  for (int i = 0; i < 8; ++i) {
    int cc = c0 + ty + i * 8;
    __hip_bfloat16 a = tile[tx * 2][ty + i * 8];
    __hip_bfloat16 b = tile[tx * 2 + 1][ty + i * 8];
    unsigned short ua = *(unsigned short*)&a, ub = *(unsigned short*)&b;
    unsigned int packed = (unsigned)ua | ((unsigned)ub << 16);
    *(unsigned int*)(op + (size_t)cc * R + r0 + tx * 2) = packed;
  }
}

// ---------------- 8-phase persistent grouped GEMM, 256x256, BK=64 ----------------
// LDS: [buf][mat][half] of 128x64 bf16 = 8 regions x 16KB = 128 KB.
// Per K-tile, 4 phases; each stages one half-tile of t+1 and computes one
// 128x128 C-quadrant x K=64. vmcnt(6) = 3 half-tiles in flight at each wait.
template<int LD, int NT, int LDO, int NCOL, bool GELU>
__global__ __launch_bounds__(512, 2) void moe_gemm8(
    const __hip_bfloat16* __restrict__ A, const __hip_bfloat16* __restrict__ B,
    __hip_bfloat16* __restrict__ Out,
    const int* __restrict__ tile_e, const int* __restrict__ tile_row,
    const int* __restrict__ numTiles, int* __restrict__ ctr)
{
  __shared__ __align__(16) __hip_bfloat16 lds[8][8192];
  __shared__ int s_u;
  const int t = threadIdx.x, lane = t & 63, w = t >> 6;
  const int wm = w >> 2, wn = w & 3;
  const int fr = lane & 15, fkg = lane >> 4;
  const size_t rowoff = (size_t)(w * 8 + (lane >> 3)) * LD + (((lane & 7) ^ (lane >> 3)) << 3);
  const int aoff = (wm * 64 + fr) * 64;
  const int boff = (wn * 32 + fr) * 64;
  const int swk0 = (fkg ^ (fr & 7)) * 8;
  const int swk1 = ((4 + fkg) ^ (fr & 7)) * 8;
  const int nU = *numTiles * NCOL;

  while (true) {
    __syncthreads();
    if (t == 0) s_u = atomicAdd(ctr, 1);
    __syncthreads();
    int u = s_u;
    if (u >= nU) break;
    int col0 = (u % NCOL) * 256;
    int tile = u / NCOL;
    int e = tile_e[tile];
    int row0 = tile_row[tile];
    const __hip_bfloat16* Ab = A + (size_t)row0 * LD;
    const __hip_bfloat16* Bb = B + (size_t)e * ((size_t)FDIM * DDIM) + (size_t)col0 * LD;

    auto STAGEH = [&](const __hip_bfloat16* base, int mat, int half, int tt) {
      __hip_bfloat16* d = &lds[(((tt & 1) << 2) | (mat << 1) | half)][0] + w * 512;
      const __hip_bfloat16* s = base + (size_t)(half * 128) * LD + (size_t)tt * 64 + rowoff;
      GLOAD16(d, s);
      GLOAD16(d + 4096, s + (size_t)64 * LD);
    };

    f32x4 acc[4][4][2] = {};
    // prologue: tile 0 halves in need-order A0, B0, B1, A1
    STAGEH(Ab, 0, 0, 0); STAGEH(Bb, 1, 0, 0); STAGEH(Bb, 1, 1, 0); STAGEH(Ab, 0, 1, 0);

    for (int kt = 0; kt < NT; ++kt) {
      const int buf = kt & 1;
      const bool pre = (kt + 1) < NT;
      const __hip_bfloat16* A0r = &lds[(buf << 2) | 0][0];
      const __hip_bfloat16* A1r = &lds[(buf << 2) | 1][0];
      const __hip_bfloat16* B0r = &lds[(buf << 2) | 2][0];
      const __hip_bfloat16* B1r = &lds[(buf << 2) | 3][0];
      s16x8 af[4][2], b0[2][2], b1[2][2];

      // ---- phase 1: quadrant (0,0) ----
      if (pre) STAGEH(Ab, 0, 0, kt + 1);
      if (pre) { WAITVM(6); } else { WAITVM(0); }
      __builtin_amdgcn_s_barrier();
      MEMFENCE;
#pragma unroll
      for (int m = 0; m < 4; ++m) {
        af[m][0] = *(const s16x8*)(A0r + aoff + m * 1024 + swk0);
        af[m][1] = *(const s16x8*)(A0r + aoff + m * 1024 + swk1);
      }
#pragma unroll
      for (int n = 0; n < 2; ++n) {
        b0[n][0] = *(const s16x8*)(B0r + boff + n * 1024 + swk0);
        b0[n][1] = *(const s16x8*)(B0r + boff + n * 1024 + swk1);
      }
      __builtin_amdgcn_s_setprio(1);
#pragma unroll
      for (int kk = 0; kk < 2; ++kk)
#pragma unroll
        for (int m = 0; m < 4; ++m)
#pragma unroll
          for (int n = 0; n < 2; ++n)
            acc[0][m][n] = __builtin_amdgcn_mfma_f32_16x16x32_bf16(af[m][kk], b0[n][kk], acc[0][m][n], 0, 0, 0);
      __builtin_amdgcn_s_setprio(0);
      MEMFENCE;

      // ---- phase 2: quadrant (0,1) ----
      if (pre) STAGEH(Bb, 1, 0, kt + 1);
      if (pre) { WAITVM(6); }
      __builtin_amdgcn_s_barrier();
      MEMFENCE;
#pragma unroll
      for (int n = 0; n < 2; ++n) {
        b1[n][0] = *(const s16x8*)(B1r + boff + n * 1024 + swk0);
        b1[n][1] = *(const s16x8*)(B1r + boff + n * 1024 + swk1);
      }
      __builtin_amdgcn_s_setprio(1);
#pragma unroll
      for (int kk = 0; kk < 2; ++kk)
#pragma unroll
        for (int m = 0; m < 4; ++m)
#pragma unroll
          for (int n = 0; n < 2; ++n)
            acc[1][m][n] = __builtin_amdgcn_mfma_f32_16x16x32_bf16(af[m][kk], b1[n][kk], acc[1][m][n], 0, 0, 0);
      __builtin_amdgcn_s_setprio(0);
      MEMFENCE;

      // ---- phase 3: quadrant (1,1) ----
      if (pre) STAGEH(Bb, 1, 1, kt + 1);
      if (pre) { WAITVM(6); }
      __builtin_amdgcn_s_barrier();
      MEMFENCE;
#pragma unroll
      for (int m = 0; m < 4; ++m) {
        af[m][0] = *(const s16x8*)(A1r + aoff + m * 1024 + swk0);
        af[m][1] = *(const s16x8*)(A1r + aoff + m * 1024 + swk1);
      }
      __builtin_amdgcn_s_setprio(1);
#pragma unroll
      for (int kk = 0; kk < 2; ++kk)
#pragma unroll
        for (int m = 0; m < 4; ++m)
#pragma unroll
          for (int n = 0; n < 2; ++n)
            acc[2][m][n] = __builtin_amdgcn_mfma_f32_16x16x32_bf16(af[m][kk], b1[n][kk], acc[2][m][n], 0, 0, 0);
      __builtin_amdgcn_s_setprio(0);
      MEMFENCE;

      // ---- phase 4: quadrant (1,0) ----
      if (pre) STAGEH(Ab, 0, 1, kt + 1);
      __builtin_amdgcn_s_barrier();
      MEMFENCE;
      __builtin_amdgcn_s_setprio(1);
#pragma unroll
      for (int kk = 0; kk < 2; ++kk)
#pragma unroll
        for (int m = 0; m < 4; ++m)
#pragma unroll
          for (int n = 0; n < 2; ++n)
            acc[3][m][n] = __builtin_amdgcn_mfma_f32_16x16x32_bf16(af[m][kk], b0[n][kk], acc[3][m][n], 0, 0, 0);
      __builtin_amdgcn_s_setprio(0);
      MEMFENCE;
    }

    // epilogue
    const int qmh[4] = {0, 0, 1, 1};
    const int qnh[4] = {0, 1, 1, 0};
#pragma unroll
    for (int q = 0; q < 4; ++q) {
#pragma unroll
      for (int m = 0; m < 4; ++m) {
        int r = row0 + qmh[q] * 128 + wm * 64 + m * 16 + fkg * 4;
#pragma unroll
        for (int j = 0; j < 4; ++j) {
#pragma unroll
          for (int n = 0; n < 2; ++n) {
            int c = col0 + qnh[q] * 128 + wn * 32 + n * 16 + fr;
            float v = acc[q][m][n][j];
            if (GELU) v = gelu_fast(v);
            Out[(size_t)(r + j) * LDO + c] = __float2bfloat16(v);
          }
        }
      }
    }
  }
}

// ---------------- combine: out[tok] = wa*Eout[sa] + wb*Eout[sb] ----------------
__global__ __launch_bounds__(256) void combine_kernel(
    const __hip_bfloat16* __restrict__ Eout, const int* __restrict__ tok_slot,
    const float* __restrict__ tok_w, float* __restrict__ out)
{
  int tok = blockIdx.x;
  int sa = tok_slot[tok * 2], sb = tok_slot[tok * 2 + 1];
  float wa = tok_w[tok * 2], wb = tok_w[tok * 2 + 1];
  const __hip_bfloat16* ra = Eout + (size_t)sa * DDIM;
  const __hip_bfloat16* rb = Eout + (size_t)sb * DDIM;
  float* op = out + (size_t)tok * DDIM;
  int c = threadIdx.x * 4;
  us4 va = *(const us4*)(ra + c);
  us4 vb = *(const us4*)(rb + c);
  float4 o;
  o.x = wa * bf2f(va.x) + wb * bf2f(vb.x);
  o.y = wa * bf2f(va.y) + wb * bf2f(vb.y);
  o.z = wa * bf2f(va.z) + wb * bf2f(vb.z);
  o.w = wa * bf2f(va.w) + wb * bf2f(vb.w);
  *(float4*)(op + c) = o;
}

extern "C" void kernel_launch(void* const* d_in, const int* in_sizes, int n_in,
                              void* d_out, int out_size, void* d_ws, size_t ws_size,
                              hipStream_t stream)
{
  const float* x      = (const float*)d_in[0];
  const float* gate_w = (const float*)d_in[1];
  const float* w1     = (const float*)d_in[2];
  const float* w2     = (const float*)d_in[3];
  float* out = (float*)d_out;

  char* ws = (char*)d_ws;
  size_t off = 0;
  auto alloc = [&](size_t bytes) -> void* {
    void* p = ws + off;
    off = (off + bytes + 255) & ~(size_t)255;
    return p;
  };
  int* ctrl = (int*)alloc(1024);          // zeroed control block
  int* counts     = ctrl + 0;
  int* fill       = ctrl + 8;
  int* padded_off = ctrl + 16;
  int* numTiles   = ctrl + 24;
  int* ctrA       = ctrl + 32;
  int* ctrB       = ctrl + 40;
  int*   tile_e     = (int*)alloc(MAXT * 4);
  int*   tile_row   = (int*)alloc(MAXT * 4);
  int*   tok_e      = (int*)alloc((size_t)T_TOK * 2 * 4);
  float* tok_w      = (float*)alloc((size_t)T_TOK * 2 * 4);
  int*   tok_slot   = (int*)alloc((size_t)T_TOK * 2 * 4);
  int*   pair_token = (int*)alloc((size_t)PADMAX * 4);
  __hip_bfloat16* XgEout = (__hip_bfloat16*)alloc((size_t)PADMAX * DDIM * 2); // Xg, later Eout
  __hip_bfloat16* W1t  = (__hip_bfloat16*)alloc((size_t)NEXP * FDIM * DDIM * 2);
  __hip_bfloat16* W2t  = (__hip_bfloat16*)alloc((size_t)NEXP * FDIM * DDIM * 2);
  __hip_bfloat16* Hbuf = (__hip_bfloat16*)alloc((size_t)PADMAX * FDIM * 2);
  (void)in_sizes; (void)n_in; (void)ws_size; (void)out_size;

  hipMemsetAsync(d_ws, 0, 1024, stream);

  transpose_conv<<<dim3(FDIM / 64, DDIM / 64, NEXP), 256, 0, stream>>>(w1, W1t, DDIM, FDIM);
  transpose_conv<<<dim3(DDIM / 64, FDIM / 64, NEXP), 256, 0, stream>>>(w2, W2t, FDIM, DDIM);

  gate_kernel<<<T_TOK / 4, 256, 0, stream>>>(x, gate_w, counts, tok_e, tok_w);
  scan_kernel<<<1, 64, 0, stream>>>(counts, padded_off, tile_e, tile_row, numTiles);
  init_pairs<<<(PADMAX + 255) / 256, 256, 0, stream>>>(pair_token);
  scatter_kernel<<<T_TOK / 256, 256, 0, stream>>>(tok_e, padded_off, fill,
                                                  pair_token, tok_slot);
  gather_x<<<(PADMAX * (DDIM / 8) + 255) / 256, 256, 0, stream>>>(x, pair_token, XgEout);

  // ffn1: H = gelu(Xg @ W1t[e]^T)   (K=1024, N=4096)
  moe_gemm8<DDIM, DDIM / 64, FDIM, FDIM / 256, true>
      <<<256, 512, 0, stream>>>(XgEout, W1t, Hbuf, tile_e, tile_row, numTiles, ctrA);
  // ffn2: Eout = H @ W2t[e]^T       (K=4096, N=1024)
  moe_gemm8<FDIM, FDIM / 64, DDIM, DDIM / 256, false>
      <<<256, 512, 0, stream>>>(Hbuf, W2t, XgEout, tile_e, tile_row, numTiles, ctrB);

  combine_kernel<<<T_TOK, 256, 0, stream>>>(XgEout, tok_slot, tok_w, out);
}

// Round 5
// 786.332 us; speedup vs baseline: 1.1467x; 1.0360x over previous
//
#include <hip/hip_runtime.h>
#include <hip/hip_bf16.h>

typedef short s16x8 __attribute__((ext_vector_type(8)));
typedef float f32x4 __attribute__((ext_vector_type(4)));
typedef unsigned short us8 __attribute__((ext_vector_type(8)));
typedef unsigned short us4 __attribute__((ext_vector_type(4)));

#define T_TOK 8192
#define DDIM 1024
#define NEXP 8
#define FDIM 4096
#define MAXT 72
#define PADMAX (16384 + NEXP * 256)

#define GLOAD16(dst, src) \
  __builtin_amdgcn_global_load_lds((const __attribute__((address_space(1))) unsigned int*)(src), \
                                   (__attribute__((address_space(3))) unsigned int*)(dst), 16, 0, 0)
#define WAITVM(n) asm volatile("s_waitcnt vmcnt(" #n ")" ::: "memory")
#define MEMFENCE asm volatile("" ::: "memory")

__device__ __forceinline__ float gelu_fast(float x) {
  float u = 0.7978845608028654f * x * (1.0f + 0.044715f * x * x);
  float t = __expf(-2.0f * fabsf(u));
  float th = (1.0f - t) / (1.0f + t);
  th = u >= 0.f ? th : -th;
  return 0.5f * x * (1.0f + th);
}
__device__ __forceinline__ float bf2f(unsigned short v) {
  return __uint_as_float((unsigned)v << 16);
}

// ---------------- gating ----------------
__global__ __launch_bounds__(256) void gate_kernel(
    const float* __restrict__ x, const float* __restrict__ gw,
    int* __restrict__ counts, int* __restrict__ tok_e, float* __restrict__ tok_w)
{
  int lane = threadIdx.x & 63;
  int tok = blockIdx.x * 4 + (threadIdx.x >> 6);
  const float* xr = x + (size_t)tok * DDIM;
  float acc[NEXP];
#pragma unroll
  for (int e = 0; e < NEXP; ++e) acc[e] = 0.f;
  for (int i = 0; i < DDIM / 64; ++i) {
    int d = i * 64 + lane;
    float xv = xr[d];
    const float* g = gw + (size_t)d * NEXP;
#pragma unroll
    for (int e = 0; e < NEXP; ++e) acc[e] += xv * g[e];
  }
#pragma unroll
  for (int off = 32; off > 0; off >>= 1) {
#pragma unroll
    for (int e = 0; e < NEXP; ++e) acc[e] += __shfl_xor(acc[e], off);
  }
  if (lane == 0) {
    int i1 = 0; float m1 = acc[0];
#pragma unroll
    for (int e = 1; e < NEXP; ++e) if (acc[e] > m1) { m1 = acc[e]; i1 = e; }
    int i2 = -1; float m2 = -3.4e38f;
#pragma unroll
    for (int e = 0; e < NEXP; ++e) if (e != i1 && acc[e] > m2) { m2 = acc[e]; i2 = e; }
    float w1 = 1.f / (1.f + expf(m2 - m1));
    tok_e[tok * 2] = i1; tok_e[tok * 2 + 1] = i2;
    tok_w[tok * 2] = w1; tok_w[tok * 2 + 1] = 1.f - w1;
    atomicAdd(&counts[i1], 1);
    atomicAdd(&counts[i2], 1);
  }
}

// ------- scan: pad to 256, tile table; also init pair_token to -1 -------
__global__ void scan_kernel(const int* __restrict__ counts, int* padded_off,
                            int* tile_e, int* tile_row, int* numTiles,
                            int* __restrict__ pair_token)
{
  if (blockIdx.x == 0) {
    for (int i = threadIdx.x; i < PADMAX; i += 256) pair_token[i] = -1;
    if (threadIdx.x == 0) {
      int off = 0, a = 0;
      for (int e = 0; e < NEXP; ++e) {
        padded_off[e] = off;
        int c = counts[e];
        int nt = (c + 255) / 256;
        for (int i = 0; i < nt; ++i) { tile_e[a] = e; tile_row[a] = off + i * 256; ++a; }
        off += nt * 256;
      }
      *numTiles = a;
    }
  }
}

__global__ void scatter_kernel(const int* __restrict__ tok_e,
                               const int* __restrict__ padded_off, int* __restrict__ fill,
                               int* __restrict__ pair_token, int* __restrict__ tok_slot)
{
  int tok = blockIdx.x * 256 + threadIdx.x;
  if (tok >= T_TOK) return;
#pragma unroll
  for (int k = 0; k < 2; ++k) {
    int e = tok_e[tok * 2 + k];
    int slot = padded_off[e] + atomicAdd(&fill[e], 1);
    pair_token[slot] = tok;
    tok_slot[tok * 2 + k] = slot;
  }
}

// ---------------- gather tokens -> bf16 rows (zeros for padding) ----------------
__global__ __launch_bounds__(256) void gather_x(
    const float* __restrict__ x, const int* __restrict__ pair_token,
    __hip_bfloat16* __restrict__ Xg)
{
  int gid = blockIdx.x * 256 + threadIdx.x;
  int r = gid >> 7;
  int c = (gid & 127) << 3;
  if (r >= PADMAX) return;
  int tk = pair_token[r];
  __hip_bfloat16 v[8];
  if (tk < 0) {
#pragma unroll
    for (int j = 0; j < 8; ++j) v[j] = __float2bfloat16(0.f);
  } else {
    const float* src = x + (size_t)tk * DDIM + c;
#pragma unroll
    for (int j = 0; j < 8; ++j) v[j] = __float2bfloat16(src[j]);
  }
  *(us8*)(Xg + (size_t)r * DDIM + c) = *(const us8*)v;
}

// ------- fp32 (R,C) -> bf16 (C,R) transpose+convert, per expert z -------
__global__ __launch_bounds__(256) void transpose_conv(
    const float* __restrict__ in, __hip_bfloat16* __restrict__ out, int R, int C)
{
  __shared__ __hip_bfloat16 tile[64][66];   // stride 33 dwords -> conflict-free
  size_t mat = (size_t)R * C;
  const float* ip = in + (size_t)blockIdx.z * mat;
  __hip_bfloat16* op = out + (size_t)blockIdx.z * mat;
  int c0 = blockIdx.x * 64, r0 = blockIdx.y * 64;
  int tx = threadIdx.x & 31, ty = threadIdx.x >> 5;
#pragma unroll
  for (int i = 0; i < 8; ++i) {
    int r = r0 + ty + i * 8;
    float2 v = *(const float2*)(ip + (size_t)r * C + c0 + tx * 2);
    tile[ty + i * 8][tx * 2]     = __float2bfloat16(v.x);
    tile[ty + i * 8][tx * 2 + 1] = __float2bfloat16(v.y);
  }
  __syncthreads();
#pragma unroll
  for (int i = 0; i < 8; ++i) {
    int cc = c0 + ty + i * 8;
    __hip_bfloat16 a = tile[tx * 2][ty + i * 8];
    __hip_bfloat16 b = tile[tx * 2 + 1][ty + i * 8];
    unsigned short ua = *(unsigned short*)&a, ub = *(unsigned short*)&b;
    unsigned int packed = (unsigned)ua | ((unsigned)ub << 16);
    *(unsigned int*)(op + (size_t)cc * R + r0 + tx * 2) = packed;
  }
}

// ---------------- 8-phase grouped GEMM, 256x256, BK=64 ----------------
// Work distribution: grid = MAXT*NCOL blocks; xcd = bid&7 owns a contiguous
// unit range; within it, supertiles of 3 tiles x SC cols so concurrent blocks
// on one XCD share A-tiles (SC-way) and B-panels (3-way) through its L2.
// Tiles interleaved tile = tl*8+xcd for load balance of dead tiles.
template<int LD, int NT, int LDO, int NCOL, int SC, bool GELU>
__global__ __launch_bounds__(512, 2) void moe_gemm8(
    const __hip_bfloat16* __restrict__ A, const __hip_bfloat16* __restrict__ B,
    __hip_bfloat16* __restrict__ Out,
    const int* __restrict__ tile_e, const int* __restrict__ tile_row,
    const int* __restrict__ numTiles)
{
  constexpr int TPX = MAXT / 8;          // 9 tiles per xcd
  constexpr int STU = 3 * SC;            // units per supertile
  constexpr int NCG = NCOL / SC;         // col groups
  const int bid = blockIdx.x;
  const int xcd = bid & 7;
  const int idx = bid >> 3;              // [0, TPX*NCOL)
  const int stg = idx / STU;
  const int within = idx % STU;
  const int colg = stg % NCG;
  const int tg = stg / NCG;
  const int tl = tg * 3 + within % 3;    // [0, TPX)
  const int col = colg * SC + within / 3;
  const int tile = tl * 8 + xcd;
  if (tile >= *numTiles) return;

  __shared__ __align__(16) __hip_bfloat16 lds[8][8192];
  const int t = threadIdx.x, lane = t & 63, w = t >> 6;
  const int wm = w >> 2, wn = w & 3;
  const int fr = lane & 15, fkg = lane >> 4;
  const size_t rowoff = (size_t)(w * 8 + (lane >> 3)) * LD + (((lane & 7) ^ (lane >> 3)) << 3);
  const int aoff = (wm * 64 + fr) * 64;
  const int boff = (wn * 32 + fr) * 64;
  const int swk0 = (fkg ^ (fr & 7)) * 8;
  const int swk1 = ((4 + fkg) ^ (fr & 7)) * 8;

  const int e = tile_e[tile];
  const int row0 = tile_row[tile];
  const int col0 = col * 256;
  const __hip_bfloat16* Ab = A + (size_t)row0 * LD;
  const __hip_bfloat16* Bb = B + (size_t)e * ((size_t)FDIM * DDIM) + (size_t)col0 * LD;

  auto STAGEH = [&](const __hip_bfloat16* base, int mat, int half, int tt) {
    __hip_bfloat16* d = &lds[(((tt & 1) << 2) | (mat << 1) | half)][0] + w * 512;
    const __hip_bfloat16* s = base + (size_t)(half * 128) * LD + (size_t)tt * 64 + rowoff;
    GLOAD16(d, s);
    GLOAD16(d + 4096, s + (size_t)64 * LD);
  };

  f32x4 acc[4][4][2] = {};
  // prologue: tile 0 halves in need-order A0, B0, B1, A1
  STAGEH(Ab, 0, 0, 0); STAGEH(Bb, 1, 0, 0); STAGEH(Bb, 1, 1, 0); STAGEH(Ab, 0, 1, 0);

  for (int kt = 0; kt < NT; ++kt) {
    const int buf = kt & 1;
    const bool pre = (kt + 1) < NT;
    const __hip_bfloat16* A0r = &lds[(buf << 2) | 0][0];
    const __hip_bfloat16* A1r = &lds[(buf << 2) | 1][0];
    const __hip_bfloat16* B0r = &lds[(buf << 2) | 2][0];
    const __hip_bfloat16* B1r = &lds[(buf << 2) | 3][0];
    s16x8 af[4][2], b0[2][2], b1[2][2];

    // ---- phase 1: quadrant (0,0) ----
    if (pre) STAGEH(Ab, 0, 0, kt + 1);
    if (pre) { WAITVM(6); } else { WAITVM(0); }
    __builtin_amdgcn_s_barrier();
    MEMFENCE;
#pragma unroll
    for (int m = 0; m < 4; ++m) {
      af[m][0] = *(const s16x8*)(A0r + aoff + m * 1024 + swk0);
      af[m][1] = *(const s16x8*)(A0r + aoff + m * 1024 + swk1);
    }
#pragma unroll
    for (int n = 0; n < 2; ++n) {
      b0[n][0] = *(const s16x8*)(B0r + boff + n * 1024 + swk0);
      b0[n][1] = *(const s16x8*)(B0r + boff + n * 1024 + swk1);
    }
    __builtin_amdgcn_s_setprio(1);
#pragma unroll
    for (int kk = 0; kk < 2; ++kk)
#pragma unroll
      for (int m = 0; m < 4; ++m)
#pragma unroll
        for (int n = 0; n < 2; ++n)
          acc[0][m][n] = __builtin_amdgcn_mfma_f32_16x16x32_bf16(af[m][kk], b0[n][kk], acc[0][m][n], 0, 0, 0);
    __builtin_amdgcn_s_setprio(0);
    MEMFENCE;

    // ---- phase 2: quadrant (0,1) ----
    if (pre) STAGEH(Bb, 1, 0, kt + 1);
    if (pre) { WAITVM(6); }
    __builtin_amdgcn_s_barrier();
    MEMFENCE;
#pragma unroll
    for (int n = 0; n < 2; ++n) {
      b1[n][0] = *(const s16x8*)(B1r + boff + n * 1024 + swk0);
      b1[n][1] = *(const s16x8*)(B1r + boff + n * 1024 + swk1);
    }
    __builtin_amdgcn_s_setprio(1);
#pragma unroll
    for (int kk = 0; kk < 2; ++kk)
#pragma unroll
      for (int m = 0; m < 4; ++m)
#pragma unroll
        for (int n = 0; n < 2; ++n)
          acc[1][m][n] = __builtin_amdgcn_mfma_f32_16x16x32_bf16(af[m][kk], b1[n][kk], acc[1][m][n], 0, 0, 0);
    __builtin_amdgcn_s_setprio(0);
    MEMFENCE;

    // ---- phase 3: quadrant (1,1) ----
    if (pre) STAGEH(Bb, 1, 1, kt + 1);
    if (pre) { WAITVM(6); }
    __builtin_amdgcn_s_barrier();
    MEMFENCE;
#pragma unroll
    for (int m = 0; m < 4; ++m) {
      af[m][0] = *(const s16x8*)(A1r + aoff + m * 1024 + swk0);
      af[m][1] = *(const s16x8*)(A1r + aoff + m * 1024 + swk1);
    }
    __builtin_amdgcn_s_setprio(1);
#pragma unroll
    for (int kk = 0; kk < 2; ++kk)
#pragma unroll
      for (int m = 0; m < 4; ++m)
#pragma unroll
        for (int n = 0; n < 2; ++n)
          acc[2][m][n] = __builtin_amdgcn_mfma_f32_16x16x32_bf16(af[m][kk], b1[n][kk], acc[2][m][n], 0, 0, 0);
    __builtin_amdgcn_s_setprio(0);
    MEMFENCE;

    // ---- phase 4: quadrant (1,0) ----
    if (pre) STAGEH(Ab, 0, 1, kt + 1);
    __builtin_amdgcn_s_barrier();
    MEMFENCE;
    __builtin_amdgcn_s_setprio(1);
#pragma unroll
    for (int kk = 0; kk < 2; ++kk)
#pragma unroll
      for (int m = 0; m < 4; ++m)
#pragma unroll
        for (int n = 0; n < 2; ++n)
          acc[3][m][n] = __builtin_amdgcn_mfma_f32_16x16x32_bf16(af[m][kk], b0[n][kk], acc[3][m][n], 0, 0, 0);
    __builtin_amdgcn_s_setprio(0);
    MEMFENCE;
  }

  // epilogue
  const int qmh[4] = {0, 0, 1, 1};
  const int qnh[4] = {0, 1, 1, 0};
#pragma unroll
  for (int q = 0; q < 4; ++q) {
#pragma unroll
    for (int m = 0; m < 4; ++m) {
      int r = row0 + qmh[q] * 128 + wm * 64 + m * 16 + fkg * 4;
#pragma unroll
      for (int j = 0; j < 4; ++j) {
#pragma unroll
        for (int n = 0; n < 2; ++n) {
          int c = col0 + qnh[q] * 128 + wn * 32 + n * 16 + fr;
          float v = acc[q][m][n][j];
          if (GELU) v = gelu_fast(v);
          Out[(size_t)(r + j) * LDO + c] = __float2bfloat16(v);
        }
      }
    }
  }
}

// ---------------- combine: out[tok] = wa*Eout[sa] + wb*Eout[sb] ----------------
__global__ __launch_bounds__(256) void combine_kernel(
    const __hip_bfloat16* __restrict__ Eout, const int* __restrict__ tok_slot,
    const float* __restrict__ tok_w, float* __restrict__ out)
{
  int tok = blockIdx.x;
  int sa = tok_slot[tok * 2], sb = tok_slot[tok * 2 + 1];
  float wa = tok_w[tok * 2], wb = tok_w[tok * 2 + 1];
  const __hip_bfloat16* ra = Eout + (size_t)sa * DDIM;
  const __hip_bfloat16* rb = Eout + (size_t)sb * DDIM;
  float* op = out + (size_t)tok * DDIM;
  int c = threadIdx.x * 4;
  us4 va = *(const us4*)(ra + c);
  us4 vb = *(const us4*)(rb + c);
  float4 o;
  o.x = wa * bf2f(va.x) + wb * bf2f(vb.x);
  o.y = wa * bf2f(va.y) + wb * bf2f(vb.y);
  o.z = wa * bf2f(va.z) + wb * bf2f(vb.z);
  o.w = wa * bf2f(va.w) + wb * bf2f(vb.w);
  *(float4*)(op + c) = o;
}

extern "C" void kernel_launch(void* const* d_in, const int* in_sizes, int n_in,
                              void* d_out, int out_size, void* d_ws, size_t ws_size,
                              hipStream_t stream)
{
  const float* x      = (const float*)d_in[0];
  const float* gate_w = (const float*)d_in[1];
  const float* w1     = (const float*)d_in[2];
  const float* w2     = (const float*)d_in[3];
  float* out = (float*)d_out;

  char* ws = (char*)d_ws;
  size_t off = 0;
  auto alloc = [&](size_t bytes) -> void* {
    void* p = ws + off;
    off = (off + bytes + 255) & ~(size_t)255;
    return p;
  };
  int* ctrl = (int*)alloc(1024);          // zeroed control block
  int* counts     = ctrl + 0;
  int* fill       = ctrl + 8;
  int* padded_off = ctrl + 16;
  int* numTiles   = ctrl + 24;
  int*   tile_e     = (int*)alloc(MAXT * 4);
  int*   tile_row   = (int*)alloc(MAXT * 4);
  int*   tok_e      = (int*)alloc((size_t)T_TOK * 2 * 4);
  float* tok_w      = (float*)alloc((size_t)T_TOK * 2 * 4);
  int*   tok_slot   = (int*)alloc((size_t)T_TOK * 2 * 4);
  int*   pair_token = (int*)alloc((size_t)PADMAX * 4);
  __hip_bfloat16* XgEout = (__hip_bfloat16*)alloc((size_t)PADMAX * DDIM * 2); // Xg, later Eout
  __hip_bfloat16* W1t  = (__hip_bfloat16*)alloc((size_t)NEXP * FDIM * DDIM * 2);
  __hip_bfloat16* W2t  = (__hip_bfloat16*)alloc((size_t)NEXP * FDIM * DDIM * 2);
  __hip_bfloat16* Hbuf = (__hip_bfloat16*)alloc((size_t)PADMAX * FDIM * 2);
  (void)in_sizes; (void)n_in; (void)ws_size; (void)out_size;

  hipMemsetAsync(d_ws, 0, 1024, stream);

  transpose_conv<<<dim3(FDIM / 64, DDIM / 64, NEXP), 256, 0, stream>>>(w1, W1t, DDIM, FDIM);
  transpose_conv<<<dim3(DDIM / 64, FDIM / 64, NEXP), 256, 0, stream>>>(w2, W2t, FDIM, DDIM);

  gate_kernel<<<T_TOK / 4, 256, 0, stream>>>(x, gate_w, counts, tok_e, tok_w);
  scan_kernel<<<1, 256, 0, stream>>>(counts, padded_off, tile_e, tile_row, numTiles,
                                     pair_token);
  scatter_kernel<<<T_TOK / 256, 256, 0, stream>>>(tok_e, padded_off, fill,
                                                  pair_token, tok_slot);
  gather_x<<<(PADMAX * (DDIM / 8) + 255) / 256, 256, 0, stream>>>(x, pair_token, XgEout);

  // ffn1: H = gelu(Xg @ W1t[e]^T)   (K=1024, N=4096), supertile 3 tiles x 8 cols
  moe_gemm8<DDIM, DDIM / 64, FDIM, FDIM / 256, 8, true>
      <<<MAXT * (FDIM / 256), 512, 0, stream>>>(XgEout, W1t, Hbuf,
                                                tile_e, tile_row, numTiles);
  // ffn2: Eout = H @ W2t[e]^T       (K=4096, N=1024), supertile 3 tiles x 4 cols
  moe_gemm8<FDIM, FDIM / 64, DDIM, DDIM / 256, 4, false>
      <<<MAXT * (DDIM / 256), 512, 0, stream>>>(Hbuf, W2t, XgEout,
                                                tile_e, tile_row, numTiles);

  combine_kernel<<<T_TOK, 256, 0, stream>>>(XgEout, tok_slot, tok_w, out);
}

// Round 6
// 750.769 us; speedup vs baseline: 1.2010x; 1.0474x over previous
//
#include <hip/hip_runtime.h>
#include <hip/hip_bf16.h>

typedef short s16x8 __attribute__((ext_vector_type(8)));
typedef float f32x4 __attribute__((ext_vector_type(4)));
typedef unsigned short us8 __attribute__((ext_vector_type(8)));
typedef unsigned short us4 __attribute__((ext_vector_type(4)));

#define T_TOK 8192
#define DDIM 1024
#define NEXP 8
#define FDIM 4096
#define MAXT 72
#define PADMAX (16384 + NEXP * 256)

#define GLOAD16(dst, src) \
  __builtin_amdgcn_global_load_lds((const __attribute__((address_space(1))) unsigned int*)(src), \
                                   (__attribute__((address_space(3))) unsigned int*)(dst), 16, 0, 0)
#define WAITVM(n) asm volatile("s_waitcnt vmcnt(" #n ")" ::: "memory")
#define MEMFENCE asm volatile("" ::: "memory")

// gelu(x) = 0.5x(1+tanh(u)) = x * sigmoid(2u), u = 0.79788456*x*(1+0.044715x^2)
// -2u = x*(-1.5957691 - 0.07135532*x^2);  sigmoid via v_exp + raw v_rcp.
__device__ __forceinline__ float gelu_fast(float x) {
  float x2 = x * x;
  float t = x * fmaf(x2, -0.07135532f, -1.5957691f);
  float e = __expf(t);
  return x * __builtin_amdgcn_rcpf(1.0f + e);
}
__device__ __forceinline__ float bf2f(unsigned short v) {
  return __uint_as_float((unsigned)v << 16);
}

// ---------------- gating ----------------
__global__ __launch_bounds__(256) void gate_kernel(
    const float* __restrict__ x, const float* __restrict__ gw,
    int* __restrict__ counts, int* __restrict__ tok_e, float* __restrict__ tok_w)
{
  int lane = threadIdx.x & 63;
  int tok = blockIdx.x * 4 + (threadIdx.x >> 6);
  const float* xr = x + (size_t)tok * DDIM;
  float acc[NEXP];
#pragma unroll
  for (int e = 0; e < NEXP; ++e) acc[e] = 0.f;
  for (int i = 0; i < DDIM / 64; ++i) {
    int d = i * 64 + lane;
    float xv = xr[d];
    const float* g = gw + (size_t)d * NEXP;
#pragma unroll
    for (int e = 0; e < NEXP; ++e) acc[e] += xv * g[e];
  }
#pragma unroll
  for (int off = 32; off > 0; off >>= 1) {
#pragma unroll
    for (int e = 0; e < NEXP; ++e) acc[e] += __shfl_xor(acc[e], off);
  }
  if (lane == 0) {
    int i1 = 0; float m1 = acc[0];
#pragma unroll
    for (int e = 1; e < NEXP; ++e) if (acc[e] > m1) { m1 = acc[e]; i1 = e; }
    int i2 = -1; float m2 = -3.4e38f;
#pragma unroll
    for (int e = 0; e < NEXP; ++e) if (e != i1 && acc[e] > m2) { m2 = acc[e]; i2 = e; }
    float w1 = 1.f / (1.f + expf(m2 - m1));
    tok_e[tok * 2] = i1; tok_e[tok * 2 + 1] = i2;
    tok_w[tok * 2] = w1; tok_w[tok * 2 + 1] = 1.f - w1;
    atomicAdd(&counts[i1], 1);
    atomicAdd(&counts[i2], 1);
  }
}

// ------- scan: pad to 256, tile table; also init pair_token to -1 -------
__global__ void scan_kernel(const int* __restrict__ counts, int* padded_off,
                            int* tile_e, int* tile_row, int* numTiles,
                            int* __restrict__ pair_token)
{
  if (blockIdx.x == 0) {
    for (int i = threadIdx.x; i < PADMAX; i += 256) pair_token[i] = -1;
    if (threadIdx.x == 0) {
      int off = 0, a = 0;
      for (int e = 0; e < NEXP; ++e) {
        padded_off[e] = off;
        int c = counts[e];
        int nt = (c + 255) / 256;
        for (int i = 0; i < nt; ++i) { tile_e[a] = e; tile_row[a] = off + i * 256; ++a; }
        off += nt * 256;
      }
      *numTiles = a;
    }
  }
}

__global__ void scatter_kernel(const int* __restrict__ tok_e,
                               const int* __restrict__ padded_off, int* __restrict__ fill,
                               int* __restrict__ pair_token, int* __restrict__ tok_slot)
{
  int tok = blockIdx.x * 256 + threadIdx.x;
  if (tok >= T_TOK) return;
#pragma unroll
  for (int k = 0; k < 2; ++k) {
    int e = tok_e[tok * 2 + k];
    int slot = padded_off[e] + atomicAdd(&fill[e], 1);
    pair_token[slot] = tok;
    tok_slot[tok * 2 + k] = slot;
  }
}

// ---------------- gather tokens -> bf16 rows (zeros for padding) ----------------
__global__ __launch_bounds__(256) void gather_x(
    const float* __restrict__ x, const int* __restrict__ pair_token,
    __hip_bfloat16* __restrict__ Xg)
{
  int gid = blockIdx.x * 256 + threadIdx.x;
  int r = gid >> 7;
  int c = (gid & 127) << 3;
  if (r >= PADMAX) return;
  int tk = pair_token[r];
  __hip_bfloat16 v[8];
  if (tk < 0) {
#pragma unroll
    for (int j = 0; j < 8; ++j) v[j] = __float2bfloat16(0.f);
  } else {
    const float* src = x + (size_t)tk * DDIM + c;
#pragma unroll
    for (int j = 0; j < 8; ++j) v[j] = __float2bfloat16(src[j]);
  }
  *(us8*)(Xg + (size_t)r * DDIM + c) = *(const us8*)v;
}

// ------- fp32 (R,C) -> bf16 (C,R) transpose+convert, per expert z -------
__global__ __launch_bounds__(256) void transpose_conv(
    const float* __restrict__ in, __hip_bfloat16* __restrict__ out, int R, int C)
{
  __shared__ __hip_bfloat16 tile[64][66];   // stride 33 dwords -> conflict-free
  size_t mat = (size_t)R * C;
  const float* ip = in + (size_t)blockIdx.z * mat;
  __hip_bfloat16* op = out + (size_t)blockIdx.z * mat;
  int c0 = blockIdx.x * 64, r0 = blockIdx.y * 64;
  int tx = threadIdx.x & 31, ty = threadIdx.x >> 5;
#pragma unroll
  for (int i = 0; i < 8; ++i) {
    int r = r0 + ty + i * 8;
    float2 v = *(const float2*)(ip + (size_t)r * C + c0 + tx * 2);
    tile[ty + i * 8][tx * 2]     = __float2bfloat16(v.x);
    tile[ty + i * 8][tx * 2 + 1] = __float2bfloat16(v.y);
  }
  __syncthreads();
#pragma unroll
  for (int i = 0; i < 8; ++i) {
    int cc = c0 + ty + i * 8;
    __hip_bfloat16 a = tile[tx * 2][ty + i * 8];
    __hip_bfloat16 b = tile[tx * 2 + 1][ty + i * 8];
    unsigned short ua = *(unsigned short*)&a, ub = *(unsigned short*)&b;
    unsigned int packed = (unsigned)ua | ((unsigned)ub << 16);
    *(unsigned int*)(op + (size_t)cc * R + r0 + tx * 2) = packed;
  }
}

// ---------------- 8-phase grouped GEMM, 256x256, BK=64 ----------------
template<int LD, int NT, int LDO, int NCOL, int SC, bool GELU>
__global__ __launch_bounds__(512, 2) void moe_gemm8(
    const __hip_bfloat16* __restrict__ A, const __hip_bfloat16* __restrict__ B,
    __hip_bfloat16* __restrict__ Out,
    const int* __restrict__ tile_e, const int* __restrict__ tile_row,
    const int* __restrict__ numTiles)
{
  constexpr int TPX = MAXT / 8;          // 9 tiles per xcd
  constexpr int STU = 3 * SC;            // units per supertile
  constexpr int NCG = NCOL / SC;         // col groups
  const int bid = blockIdx.x;
  const int xcd = bid & 7;
  const int idx = bid >> 3;              // [0, TPX*NCOL)
  const int stg = idx / STU;
  const int within = idx % STU;
  const int colg = stg % NCG;
  const int tg = stg / NCG;
  const int tl = tg * 3 + within % 3;    // [0, TPX)
  const int col = colg * SC + within / 3;
  const int tile = tl * 8 + xcd;
  if (tile >= *numTiles) return;

  __shared__ __align__(16) __hip_bfloat16 lds[8][8192];
  const int t = threadIdx.x, lane = t & 63, w = t >> 6;
  const int wm = w >> 2, wn = w & 3;
  const int fr = lane & 15, fkg = lane >> 4;
  const size_t rowoff = (size_t)(w * 8 + (lane >> 3)) * LD + (((lane & 7) ^ (lane >> 3)) << 3);
  const int aoff = (wm * 64 + fr) * 64;
  const int boff = (wn * 32 + fr) * 64;
  const int swk0 = (fkg ^ (fr & 7)) * 8;
  const int swk1 = ((4 + fkg) ^ (fr & 7)) * 8;

  const int e = tile_e[tile];
  const int row0 = tile_row[tile];
  const int col0 = col * 256;
  const __hip_bfloat16* Ab = A + (size_t)row0 * LD;
  const __hip_bfloat16* Bb = B + (size_t)e * ((size_t)FDIM * DDIM) + (size_t)col0 * LD;

  auto STAGEH = [&](const __hip_bfloat16* base, int mat, int half, int tt) {
    __hip_bfloat16* d = &lds[(((tt & 1) << 2) | (mat << 1) | half)][0] + w * 512;
    const __hip_bfloat16* s = base + (size_t)(half * 128) * LD + (size_t)tt * 64 + rowoff;
    GLOAD16(d, s);
    GLOAD16(d + 4096, s + (size_t)64 * LD);
  };

  f32x4 acc[4][4][2] = {};
  // prologue: tile 0 halves in need-order A0, B0, B1, A1
  STAGEH(Ab, 0, 0, 0); STAGEH(Bb, 1, 0, 0); STAGEH(Bb, 1, 1, 0); STAGEH(Ab, 0, 1, 0);

  for (int kt = 0; kt < NT; ++kt) {
    const int buf = kt & 1;
    const bool pre = (kt + 1) < NT;
    const __hip_bfloat16* A0r = &lds[(buf << 2) | 0][0];
    const __hip_bfloat16* A1r = &lds[(buf << 2) | 1][0];
    const __hip_bfloat16* B0r = &lds[(buf << 2) | 2][0];
    const __hip_bfloat16* B1r = &lds[(buf << 2) | 3][0];
    s16x8 af[4][2], b0[2][2], b1[2][2];

    // ---- phase 1: quadrant (0,0) ----
    if (pre) STAGEH(Ab, 0, 0, kt + 1);
    if (pre) { WAITVM(6); } else { WAITVM(0); }
    __builtin_amdgcn_s_barrier();
    MEMFENCE;
#pragma unroll
    for (int m = 0; m < 4; ++m) {
      af[m][0] = *(const s16x8*)(A0r + aoff + m * 1024 + swk0);
      af[m][1] = *(const s16x8*)(A0r + aoff + m * 1024 + swk1);
    }
#pragma unroll
    for (int n = 0; n < 2; ++n) {
      b0[n][0] = *(const s16x8*)(B0r + boff + n * 1024 + swk0);
      b0[n][1] = *(const s16x8*)(B0r + boff + n * 1024 + swk1);
    }
    __builtin_amdgcn_s_setprio(1);
#pragma unroll
    for (int kk = 0; kk < 2; ++kk)
#pragma unroll
      for (int m = 0; m < 4; ++m)
#pragma unroll
        for (int n = 0; n < 2; ++n)
          acc[0][m][n] = __builtin_amdgcn_mfma_f32_16x16x32_bf16(af[m][kk], b0[n][kk], acc[0][m][n], 0, 0, 0);
    __builtin_amdgcn_s_setprio(0);
    MEMFENCE;

    // ---- phase 2: quadrant (0,1) ----
    if (pre) STAGEH(Bb, 1, 0, kt + 1);
    if (pre) { WAITVM(6); }
    __builtin_amdgcn_s_barrier();
    MEMFENCE;
#pragma unroll
    for (int n = 0; n < 2; ++n) {
      b1[n][0] = *(const s16x8*)(B1r + boff + n * 1024 + swk0);
      b1[n][1] = *(const s16x8*)(B1r + boff + n * 1024 + swk1);
    }
    __builtin_amdgcn_s_setprio(1);
#pragma unroll
    for (int kk = 0; kk < 2; ++kk)
#pragma unroll
      for (int m = 0; m < 4; ++m)
#pragma unroll
        for (int n = 0; n < 2; ++n)
          acc[1][m][n] = __builtin_amdgcn_mfma_f32_16x16x32_bf16(af[m][kk], b1[n][kk], acc[1][m][n], 0, 0, 0);
    __builtin_amdgcn_s_setprio(0);
    MEMFENCE;

    // ---- phase 3: quadrant (1,1) ----
    if (pre) STAGEH(Bb, 1, 1, kt + 1);
    if (pre) { WAITVM(6); }
    __builtin_amdgcn_s_barrier();
    MEMFENCE;
#pragma unroll
    for (int m = 0; m < 4; ++m) {
      af[m][0] = *(const s16x8*)(A1r + aoff + m * 1024 + swk0);
      af[m][1] = *(const s16x8*)(A1r + aoff + m * 1024 + swk1);
    }
    __builtin_amdgcn_s_setprio(1);
#pragma unroll
    for (int kk = 0; kk < 2; ++kk)
#pragma unroll
      for (int m = 0; m < 4; ++m)
#pragma unroll
        for (int n = 0; n < 2; ++n)
          acc[2][m][n] = __builtin_amdgcn_mfma_f32_16x16x32_bf16(af[m][kk], b1[n][kk], acc[2][m][n], 0, 0, 0);
    __builtin_amdgcn_s_setprio(0);
    MEMFENCE;

    // ---- phase 4: quadrant (1,0) ----
    if (pre) STAGEH(Ab, 0, 1, kt + 1);
    __builtin_amdgcn_s_barrier();
    MEMFENCE;
    __builtin_amdgcn_s_setprio(1);
#pragma unroll
    for (int kk = 0; kk < 2; ++kk)
#pragma unroll
      for (int m = 0; m < 4; ++m)
#pragma unroll
        for (int n = 0; n < 2; ++n)
          acc[3][m][n] = __builtin_amdgcn_mfma_f32_16x16x32_bf16(af[m][kk], b0[n][kk], acc[3][m][n], 0, 0, 0);
    __builtin_amdgcn_s_setprio(0);
    MEMFENCE;
  }

  // ---- epilogue: row-major, 4 imm-offset stores per row ----
  // quadrant (qmh,qnh) -> acc idx: (0,0)=0 (0,1)=1 (1,1)=2 (1,0)=3
  const int cbase = col0 + wn * 32 + fr;
#pragma unroll
  for (int mh = 0; mh < 2; ++mh) {
    const int qa = mh ? 3 : 0;   // qnh = 0
    const int qb = mh ? 2 : 1;   // qnh = 1
#pragma unroll
    for (int m = 0; m < 4; ++m) {
#pragma unroll
      for (int j = 0; j < 4; ++j) {
        int r = row0 + mh * 128 + wm * 64 + m * 16 + fkg * 4 + j;
        __hip_bfloat16* p = Out + (size_t)r * LDO + cbase;
        float v0 = acc[qa][m][0][j];
        float v1 = acc[qa][m][1][j];
        float v2 = acc[qb][m][0][j];
        float v3 = acc[qb][m][1][j];
        if (GELU) {
          v0 = gelu_fast(v0); v1 = gelu_fast(v1);
          v2 = gelu_fast(v2); v3 = gelu_fast(v3);
        }
        p[0]   = __float2bfloat16(v0);
        p[16]  = __float2bfloat16(v1);
        p[128] = __float2bfloat16(v2);
        p[144] = __float2bfloat16(v3);
      }
    }
  }
}

// ---------------- combine: out[tok] = wa*Eout[sa] + wb*Eout[sb] ----------------
__global__ __launch_bounds__(256) void combine_kernel(
    const __hip_bfloat16* __restrict__ Eout, const int* __restrict__ tok_slot,
    const float* __restrict__ tok_w, float* __restrict__ out)
{
  int tok = blockIdx.x;
  int sa = tok_slot[tok * 2], sb = tok_slot[tok * 2 + 1];
  float wa = tok_w[tok * 2], wb = tok_w[tok * 2 + 1];
  const __hip_bfloat16* ra = Eout + (size_t)sa * DDIM;
  const __hip_bfloat16* rb = Eout + (size_t)sb * DDIM;
  float* op = out + (size_t)tok * DDIM;
  int c = threadIdx.x * 4;
  us4 va = *(const us4*)(ra + c);
  us4 vb = *(const us4*)(rb + c);
  float4 o;
  o.x = wa * bf2f(va.x) + wb * bf2f(vb.x);
  o.y = wa * bf2f(va.y) + wb * bf2f(vb.y);
  o.z = wa * bf2f(va.z) + wb * bf2f(vb.z);
  o.w = wa * bf2f(va.w) + wb * bf2f(vb.w);
  *(float4*)(op + c) = o;
}

extern "C" void kernel_launch(void* const* d_in, const int* in_sizes, int n_in,
                              void* d_out, int out_size, void* d_ws, size_t ws_size,
                              hipStream_t stream)
{
  const float* x      = (const float*)d_in[0];
  const float* gate_w = (const float*)d_in[1];
  const float* w1     = (const float*)d_in[2];
  const float* w2     = (const float*)d_in[3];
  float* out = (float*)d_out;

  char* ws = (char*)d_ws;
  size_t off = 0;
  auto alloc = [&](size_t bytes) -> void* {
    void* p = ws + off;
    off = (off + bytes + 255) & ~(size_t)255;
    return p;
  };
  int* ctrl = (int*)alloc(1024);          // zeroed control block
  int* counts     = ctrl + 0;
  int* fill       = ctrl + 8;
  int* padded_off = ctrl + 16;
  int* numTiles   = ctrl + 24;
  int*   tile_e     = (int*)alloc(MAXT * 4);
  int*   tile_row   = (int*)alloc(MAXT * 4);
  int*   tok_e      = (int*)alloc((size_t)T_TOK * 2 * 4);
  float* tok_w      = (float*)alloc((size_t)T_TOK * 2 * 4);
  int*   tok_slot   = (int*)alloc((size_t)T_TOK * 2 * 4);
  int*   pair_token = (int*)alloc((size_t)PADMAX * 4);
  __hip_bfloat16* XgEout = (__hip_bfloat16*)alloc((size_t)PADMAX * DDIM * 2); // Xg, later Eout
  __hip_bfloat16* W1t  = (__hip_bfloat16*)alloc((size_t)NEXP * FDIM * DDIM * 2);
  __hip_bfloat16* W2t  = (__hip_bfloat16*)alloc((size_t)NEXP * FDIM * DDIM * 2);
  __hip_bfloat16* Hbuf = (__hip_bfloat16*)alloc((size_t)PADMAX * FDIM * 2);
  (void)in_sizes; (void)n_in; (void)ws_size; (void)out_size;

  hipMemsetAsync(d_ws, 0, 1024, stream);

  transpose_conv<<<dim3(FDIM / 64, DDIM / 64, NEXP), 256, 0, stream>>>(w1, W1t, DDIM, FDIM);
  transpose_conv<<<dim3(DDIM / 64, FDIM / 64, NEXP), 256, 0, stream>>>(w2, W2t, FDIM, DDIM);

  gate_kernel<<<T_TOK / 4, 256, 0, stream>>>(x, gate_w, counts, tok_e, tok_w);
  scan_kernel<<<1, 256, 0, stream>>>(counts, padded_off, tile_e, tile_row, numTiles,
                                     pair_token);
  scatter_kernel<<<T_TOK / 256, 256, 0, stream>>>(tok_e, padded_off, fill,
                                                  pair_token, tok_slot);
  gather_x<<<(PADMAX * (DDIM / 8) + 255) / 256, 256, 0, stream>>>(x, pair_token, XgEout);

  // ffn1: H = gelu(Xg @ W1t[e]^T)   (K=1024, N=4096), supertile 3 tiles x 8 cols
  moe_gemm8<DDIM, DDIM / 64, FDIM, FDIM / 256, 8, true>
      <<<MAXT * (FDIM / 256), 512, 0, stream>>>(XgEout, W1t, Hbuf,
                                                tile_e, tile_row, numTiles);
  // ffn2: Eout = H @ W2t[e]^T       (K=4096, N=1024), supertile 3 tiles x 4 cols
  moe_gemm8<FDIM, FDIM / 64, DDIM, DDIM / 256, 4, false>
      <<<MAXT * (DDIM / 256), 512, 0, stream>>>(Hbuf, W2t, XgEout,
                                                tile_e, tile_row, numTiles);

  combine_kernel<<<T_TOK, 256, 0, stream>>>(XgEout, tok_slot, tok_w, out);
}

// Round 8
// 746.751 us; speedup vs baseline: 1.2075x; 1.0054x over previous
//
#include <hip/hip_runtime.h>
#include <hip/hip_bf16.h>

typedef short s16x8 __attribute__((ext_vector_type(8)));
typedef float f32x4 __attribute__((ext_vector_type(4)));
typedef float f32x2 __attribute__((ext_vector_type(2)));
typedef unsigned short us8 __attribute__((ext_vector_type(8)));
typedef unsigned short us4 __attribute__((ext_vector_type(4)));

#define T_TOK 8192
#define DDIM 1024
#define NEXP 8
#define FDIM 4096
#define MAXT 72
#define PADMAX (16384 + NEXP * 256)

#define GLOAD16(dst, src) \
  __builtin_amdgcn_global_load_lds((const __attribute__((address_space(1))) unsigned int*)(src), \
                                   (__attribute__((address_space(3))) unsigned int*)(dst), 16, 0, 0)
#define WAITVM(n) asm volatile("s_waitcnt vmcnt(" #n ")" ::: "memory")
#define MEMFENCE asm volatile("" ::: "memory")

// gelu(x) = x * sigmoid(x*(1.5957691 + 0.07135532 x^2)); exp+rcp form
__device__ __forceinline__ float gelu_fast(float x) {
  float x2 = x * x;
  float t = x * fmaf(x2, -0.07135532f, -1.5957691f);
  float e = __expf(t);
  return x * __builtin_amdgcn_rcpf(1.0f + e);
}
__device__ __forceinline__ float bf2f(unsigned short v) {
  return __uint_as_float((unsigned)v << 16);
}

// ---------------- gating ----------------
__global__ __launch_bounds__(256) void gate_kernel(
    const float* __restrict__ x, const float* __restrict__ gw,
    int* __restrict__ counts, int* __restrict__ tok_e, float* __restrict__ tok_w)
{
  int lane = threadIdx.x & 63;
  int tok = blockIdx.x * 4 + (threadIdx.x >> 6);
  const float* xr = x + (size_t)tok * DDIM;
  float acc[NEXP];
#pragma unroll
  for (int e = 0; e < NEXP; ++e) acc[e] = 0.f;
  for (int i = 0; i < DDIM / 64; ++i) {
    int d = i * 64 + lane;
    float xv = xr[d];
    const float* g = gw + (size_t)d * NEXP;
#pragma unroll
    for (int e = 0; e < NEXP; ++e) acc[e] += xv * g[e];
  }
#pragma unroll
  for (int off = 32; off > 0; off >>= 1) {
#pragma unroll
    for (int e = 0; e < NEXP; ++e) acc[e] += __shfl_xor(acc[e], off);
  }
  if (lane == 0) {
    int i1 = 0; float m1 = acc[0];
#pragma unroll
    for (int e = 1; e < NEXP; ++e) if (acc[e] > m1) { m1 = acc[e]; i1 = e; }
    int i2 = -1; float m2 = -3.4e38f;
#pragma unroll
    for (int e = 0; e < NEXP; ++e) if (e != i1 && acc[e] > m2) { m2 = acc[e]; i2 = e; }
    float w1 = 1.f / (1.f + expf(m2 - m1));
    tok_e[tok * 2] = i1; tok_e[tok * 2 + 1] = i2;
    tok_w[tok * 2] = w1; tok_w[tok * 2 + 1] = 1.f - w1;
    atomicAdd(&counts[i1], 1);
    atomicAdd(&counts[i2], 1);
  }
}

// ------- scan: pad to 256, tile table; also init pair_token to -1 -------
__global__ void scan_kernel(const int* __restrict__ counts, int* padded_off,
                            int* tile_e, int* tile_row, int* numTiles,
                            int* __restrict__ pair_token)
{
  if (blockIdx.x == 0) {
    for (int i = threadIdx.x; i < PADMAX; i += 256) pair_token[i] = -1;
    if (threadIdx.x == 0) {
      int off = 0, a = 0;
      for (int e = 0; e < NEXP; ++e) {
        padded_off[e] = off;
        int c = counts[e];
        int nt = (c + 255) / 256;
        for (int i = 0; i < nt; ++i) { tile_e[a] = e; tile_row[a] = off + i * 256; ++a; }
        off += nt * 256;
      }
      *numTiles = a;
    }
  }
}

__global__ void scatter_kernel(const int* __restrict__ tok_e,
                               const int* __restrict__ padded_off, int* __restrict__ fill,
                               int* __restrict__ pair_token, int* __restrict__ tok_slot)
{
  int tok = blockIdx.x * 256 + threadIdx.x;
  if (tok >= T_TOK) return;
#pragma unroll
  for (int k = 0; k < 2; ++k) {
    int e = tok_e[tok * 2 + k];
    int slot = padded_off[e] + atomicAdd(&fill[e], 1);
    pair_token[slot] = tok;
    tok_slot[tok * 2 + k] = slot;
  }
}

// ---------------- gather tokens -> bf16 rows (zeros for padding) ----------------
__global__ __launch_bounds__(256) void gather_x(
    const float* __restrict__ x, const int* __restrict__ pair_token,
    __hip_bfloat16* __restrict__ Xg)
{
  int gid = blockIdx.x * 256 + threadIdx.x;
  int r = gid >> 7;
  int c = (gid & 127) << 3;
  if (r >= PADMAX) return;
  int tk = pair_token[r];
  __hip_bfloat16 v[8];
  if (tk < 0) {
#pragma unroll
    for (int j = 0; j < 8; ++j) v[j] = __float2bfloat16(0.f);
  } else {
    const float* src = x + (size_t)tk * DDIM + c;
    f32x4 a = __builtin_nontemporal_load((const f32x4*)src);
    f32x4 b = __builtin_nontemporal_load((const f32x4*)(src + 4));
#pragma unroll
    for (int j = 0; j < 4; ++j) v[j] = __float2bfloat16(a[j]);
#pragma unroll
    for (int j = 0; j < 4; ++j) v[4 + j] = __float2bfloat16(b[j]);
  }
  *(us8*)(Xg + (size_t)r * DDIM + c) = *(const us8*)v;
}

// ------- fp32 (R,C) -> bf16 (C,R) transpose+convert, per expert z -------
// nt loads: the fp32 weights are read exactly once -> don't evict L3.
__global__ __launch_bounds__(256) void transpose_conv(
    const float* __restrict__ in, __hip_bfloat16* __restrict__ out, int R, int C)
{
  __shared__ __hip_bfloat16 tile[64][66];   // stride 33 dwords -> conflict-free
  size_t mat = (size_t)R * C;
  const float* ip = in + (size_t)blockIdx.z * mat;
  __hip_bfloat16* op = out + (size_t)blockIdx.z * mat;
  int c0 = blockIdx.x * 64, r0 = blockIdx.y * 64;
  int tx = threadIdx.x & 31, ty = threadIdx.x >> 5;
#pragma unroll
  for (int i = 0; i < 8; ++i) {
    int r = r0 + ty + i * 8;
    f32x2 v = __builtin_nontemporal_load(
        (const f32x2*)(ip + (size_t)r * C + c0 + tx * 2));
    tile[ty + i * 8][tx * 2]     = __float2bfloat16(v[0]);
    tile[ty + i * 8][tx * 2 + 1] = __float2bfloat16(v[1]);
  }
  __syncthreads();
#pragma unroll
  for (int i = 0; i < 8; ++i) {
    int cc = c0 + ty + i * 8;
    __hip_bfloat16 a = tile[tx * 2][ty + i * 8];
    __hip_bfloat16 b = tile[tx * 2 + 1][ty + i * 8];
    unsigned short ua = *(unsigned short*)&a, ub = *(unsigned short*)&b;
    unsigned int packed = (unsigned)ua | ((unsigned)ub << 16);
    *(unsigned int*)(op + (size_t)cc * R + r0 + tx * 2) = packed;
  }
}

// ---------------- 8-phase grouped GEMM, 256x256, BK=64 ----------------
template<int LD, int NT, int LDO, int NCOL, int SC, bool GELU>
__global__ __launch_bounds__(512, 2) void moe_gemm8(
    const __hip_bfloat16* __restrict__ A, const __hip_bfloat16* __restrict__ B,
    __hip_bfloat16* __restrict__ Out,
    const int* __restrict__ tile_e, const int* __restrict__ tile_row,
    const int* __restrict__ numTiles)
{
  constexpr int TPX = MAXT / 8;          // 9 tiles per xcd
  constexpr int STU = 3 * SC;            // units per supertile
  constexpr int NCG = NCOL / SC;         // col groups
  const int bid = blockIdx.x;
  const int xcd = bid & 7;
  const int idx = bid >> 3;              // [0, TPX*NCOL)
  const int stg = idx / STU;
  const int within = idx % STU;
  const int colg = stg % NCG;
  const int tg = stg / NCG;
  const int tl = tg * 3 + within % 3;    // [0, TPX)
  const int col = colg * SC + within / 3;
  const int tile = tl * 8 + xcd;
  if (tile >= *numTiles) return;

  __shared__ __align__(16) __hip_bfloat16 lds[8][8192];
  const int t = threadIdx.x, lane = t & 63, w = t >> 6;
  const int wm = w >> 2, wn = w & 3;
  const int fr = lane & 15, fkg = lane >> 4;
  const size_t rowoff = (size_t)(w * 8 + (lane >> 3)) * LD + (((lane & 7) ^ (lane >> 3)) << 3);
  const int aoff = (wm * 64 + fr) * 64;
  const int boff = (wn * 32 + fr) * 64;
  const int swk0 = (fkg ^ (fr & 7)) * 8;
  const int swk1 = ((4 + fkg) ^ (fr & 7)) * 8;

  const int e = tile_e[tile];
  const int row0 = tile_row[tile];
  const int col0 = col * 256;
  const __hip_bfloat16* Ab = A + (size_t)row0 * LD;
  const __hip_bfloat16* Bb = B + (size_t)e * ((size_t)FDIM * DDIM) + (size_t)col0 * LD;

  auto STAGEH = [&](const __hip_bfloat16* base, int mat, int half, int tt) {
    __hip_bfloat16* d = &lds[(((tt & 1) << 2) | (mat << 1) | half)][0] + w * 512;
    const __hip_bfloat16* s = base + (size_t)(half * 128) * LD + (size_t)tt * 64 + rowoff;
    GLOAD16(d, s);
    GLOAD16(d + 4096, s + (size_t)64 * LD);
  };

  f32x4 acc[4][4][2] = {};
  // prologue: tile 0 halves in need-order A0, B0, B1, A1
  STAGEH(Ab, 0, 0, 0); STAGEH(Bb, 1, 0, 0); STAGEH(Bb, 1, 1, 0); STAGEH(Ab, 0, 1, 0);

  for (int kt = 0; kt < NT; ++kt) {
    const int buf = kt & 1;
    const bool pre = (kt + 1) < NT;
    const __hip_bfloat16* A0r = &lds[(buf << 2) | 0][0];
    const __hip_bfloat16* A1r = &lds[(buf << 2) | 1][0];
    const __hip_bfloat16* B0r = &lds[(buf << 2) | 2][0];
    const __hip_bfloat16* B1r = &lds[(buf << 2) | 3][0];
    s16x8 af[4][2], b0[2][2], b1[2][2];

    // ---- phase 1: quadrant (0,0) ----
    if (pre) STAGEH(Ab, 0, 0, kt + 1);
    if (pre) { WAITVM(6); } else { WAITVM(0); }
    __builtin_amdgcn_s_barrier();
    MEMFENCE;
#pragma unroll
    for (int m = 0; m < 4; ++m) {
      af[m][0] = *(const s16x8*)(A0r + aoff + m * 1024 + swk0);
      af[m][1] = *(const s16x8*)(A0r + aoff + m * 1024 + swk1);
    }
#pragma unroll
    for (int n = 0; n < 2; ++n) {
      b0[n][0] = *(const s16x8*)(B0r + boff + n * 1024 + swk0);
      b0[n][1] = *(const s16x8*)(B0r + boff + n * 1024 + swk1);
    }
    __builtin_amdgcn_s_setprio(1);
#pragma unroll
    for (int kk = 0; kk < 2; ++kk)
#pragma unroll
      for (int m = 0; m < 4; ++m)
#pragma unroll
        for (int n = 0; n < 2; ++n)
          acc[0][m][n] = __builtin_amdgcn_mfma_f32_16x16x32_bf16(af[m][kk], b0[n][kk], acc[0][m][n], 0, 0, 0);
    __builtin_amdgcn_s_setprio(0);
    MEMFENCE;

    // ---- phase 2: quadrant (0,1) ----
    if (pre) STAGEH(Bb, 1, 0, kt + 1);
    if (pre) { WAITVM(6); }
    __builtin_amdgcn_s_barrier();
    MEMFENCE;
#pragma unroll
    for (int n = 0; n < 2; ++n) {
      b1[n][0] = *(const s16x8*)(B1r + boff + n * 1024 + swk0);
      b1[n][1] = *(const s16x8*)(B1r + boff + n * 1024 + swk1);
    }
    __builtin_amdgcn_s_setprio(1);
#pragma unroll
    for (int kk = 0; kk < 2; ++kk)
#pragma unroll
      for (int m = 0; m < 4; ++m)
#pragma unroll
        for (int n = 0; n < 2; ++n)
          acc[1][m][n] = __builtin_amdgcn_mfma_f32_16x16x32_bf16(af[m][kk], b1[n][kk], acc[1][m][n], 0, 0, 0);
    __builtin_amdgcn_s_setprio(0);
    MEMFENCE;

    // ---- phase 3: quadrant (1,1) ----
    if (pre) STAGEH(Bb, 1, 1, kt + 1);
    if (pre) { WAITVM(6); }
    __builtin_amdgcn_s_barrier();
    MEMFENCE;
#pragma unroll
    for (int m = 0; m < 4; ++m) {
      af[m][0] = *(const s16x8*)(A1r + aoff + m * 1024 + swk0);
      af[m][1] = *(const s16x8*)(A1r + aoff + m * 1024 + swk1);
    }
    __builtin_amdgcn_s_setprio(1);
#pragma unroll
    for (int kk = 0; kk < 2; ++kk)
#pragma unroll
      for (int m = 0; m < 4; ++m)
#pragma unroll
        for (int n = 0; n < 2; ++n)
          acc[2][m][n] = __builtin_amdgcn_mfma_f32_16x16x32_bf16(af[m][kk], b1[n][kk], acc[2][m][n], 0, 0, 0);
    __builtin_amdgcn_s_setprio(0);
    MEMFENCE;

    // ---- phase 4: quadrant (1,0) ----
    if (pre) STAGEH(Ab, 0, 1, kt + 1);
    __builtin_amdgcn_s_barrier();
    MEMFENCE;
    __builtin_amdgcn_s_setprio(1);
#pragma unroll
    for (int kk = 0; kk < 2; ++kk)
#pragma unroll
      for (int m = 0; m < 4; ++m)
#pragma unroll
        for (int n = 0; n < 2; ++n)
          acc[3][m][n] = __builtin_amdgcn_mfma_f32_16x16x32_bf16(af[m][kk], b0[n][kk], acc[3][m][n], 0, 0, 0);
    __builtin_amdgcn_s_setprio(0);
    MEMFENCE;
  }

  // ---- epilogue: row-major, 4 imm-offset stores per row ----
  const int cbase = col0 + wn * 32 + fr;
#pragma unroll
  for (int mh = 0; mh < 2; ++mh) {
    const int qa = mh ? 3 : 0;   // qnh = 0
    const int qb = mh ? 2 : 1;   // qnh = 1
#pragma unroll
    for (int m = 0; m < 4; ++m) {
#pragma unroll
      for (int j = 0; j < 4; ++j) {
        int r = row0 + mh * 128 + wm * 64 + m * 16 + fkg * 4 + j;
        __hip_bfloat16* p = Out + (size_t)r * LDO + cbase;
        float v0 = acc[qa][m][0][j];
        float v1 = acc[qa][m][1][j];
        float v2 = acc[qb][m][0][j];
        float v3 = acc[qb][m][1][j];
        if (GELU) {
          v0 = gelu_fast(v0); v1 = gelu_fast(v1);
          v2 = gelu_fast(v2); v3 = gelu_fast(v3);
        }
        p[0]   = __float2bfloat16(v0);
        p[16]  = __float2bfloat16(v1);
        p[128] = __float2bfloat16(v2);
        p[144] = __float2bfloat16(v3);
      }
    }
  }
}

// ---------------- combine: out[tok] = wa*Eout[sa] + wb*Eout[sb] ----------------
__global__ __launch_bounds__(256) void combine_kernel(
    const __hip_bfloat16* __restrict__ Eout, const int* __restrict__ tok_slot,
    const float* __restrict__ tok_w, float* __restrict__ out)
{
  int tok = blockIdx.x;
  int sa = tok_slot[tok * 2], sb = tok_slot[tok * 2 + 1];
  float wa = tok_w[tok * 2], wb = tok_w[tok * 2 + 1];
  const __hip_bfloat16* ra = Eout + (size_t)sa * DDIM;
  const __hip_bfloat16* rb = Eout + (size_t)sb * DDIM;
  float* op = out + (size_t)tok * DDIM;
  int c = threadIdx.x * 4;
  us4 va = *(const us4*)(ra + c);
  us4 vb = *(const us4*)(rb + c);
  float4 o;
  o.x = wa * bf2f(va.x) + wb * bf2f(vb.x);
  o.y = wa * bf2f(va.y) + wb * bf2f(vb.y);
  o.z = wa * bf2f(va.z) + wb * bf2f(vb.z);
  o.w = wa * bf2f(va.w) + wb * bf2f(vb.w);
  *(float4*)(op + c) = o;
}

extern "C" void kernel_launch(void* const* d_in, const int* in_sizes, int n_in,
                              void* d_out, int out_size, void* d_ws, size_t ws_size,
                              hipStream_t stream)
{
  const float* x      = (const float*)d_in[0];
  const float* gate_w = (const float*)d_in[1];
  const float* w1     = (const float*)d_in[2];
  const float* w2     = (const float*)d_in[3];
  float* out = (float*)d_out;

  char* ws = (char*)d_ws;
  size_t off = 0;
  auto alloc = [&](size_t bytes) -> void* {
    void* p = ws + off;
    off = (off + bytes + 255) & ~(size_t)255;
    return p;
  };
  int* ctrl = (int*)alloc(1024);          // zeroed control block
  int* counts     = ctrl + 0;
  int* fill       = ctrl + 8;
  int* padded_off = ctrl + 16;
  int* numTiles   = ctrl + 24;
  int*   tile_e     = (int*)alloc(MAXT * 4);
  int*   tile_row   = (int*)alloc(MAXT * 4);
  int*   tok_e      = (int*)alloc((size_t)T_TOK * 2 * 4);
  float* tok_w      = (float*)alloc((size_t)T_TOK * 2 * 4);
  int*   tok_slot   = (int*)alloc((size_t)T_TOK * 2 * 4);
  int*   pair_token = (int*)alloc((size_t)PADMAX * 4);
  __hip_bfloat16* XgEout = (__hip_bfloat16*)alloc((size_t)PADMAX * DDIM * 2); // Xg, later Eout
  __hip_bfloat16* W1t  = (__hip_bfloat16*)alloc((size_t)NEXP * FDIM * DDIM * 2);
  __hip_bfloat16* W2t  = (__hip_bfloat16*)alloc((size_t)NEXP * FDIM * DDIM * 2);
  __hip_bfloat16* Hbuf = (__hip_bfloat16*)alloc((size_t)PADMAX * FDIM * 2);
  (void)in_sizes; (void)n_in; (void)ws_size; (void)out_size;

  (void)hipMemsetAsync(d_ws, 0, 1024, stream);

  // ---- cache-choreographed order ----
  // routing first (small, x-resident), then W1 transpose, ffn1 (L3: W1t+Xg+H),
  // then W2 transpose, ffn2 (L3: H+W2t), then combine (Eout L2/L3-hot).
  gate_kernel<<<T_TOK / 4, 256, 0, stream>>>(x, gate_w, counts, tok_e, tok_w);
  scan_kernel<<<1, 256, 0, stream>>>(counts, padded_off, tile_e, tile_row, numTiles,
                                     pair_token);
  scatter_kernel<<<T_TOK / 256, 256, 0, stream>>>(tok_e, padded_off, fill,
                                                  pair_token, tok_slot);
  gather_x<<<(PADMAX * (DDIM / 8) + 255) / 256, 256, 0, stream>>>(x, pair_token, XgEout);

  transpose_conv<<<dim3(FDIM / 64, DDIM / 64, NEXP), 256, 0, stream>>>(w1, W1t, DDIM, FDIM);

  // ffn1: H = gelu(Xg @ W1t[e]^T)   (K=1024, N=4096), supertile 3 tiles x 8 cols
  moe_gemm8<DDIM, DDIM / 64, FDIM, FDIM / 256, 8, true>
      <<<MAXT * (FDIM / 256), 512, 0, stream>>>(XgEout, W1t, Hbuf,
                                                tile_e, tile_row, numTiles);

  transpose_conv<<<dim3(DDIM / 64, FDIM / 64, NEXP), 256, 0, stream>>>(w2, W2t, FDIM, DDIM);

  // ffn2: Eout = H @ W2t[e]^T       (K=4096, N=1024), supertile 3 tiles x 4 cols
  moe_gemm8<FDIM, FDIM / 64, DDIM, DDIM / 256, 4, false>
      <<<MAXT * (DDIM / 256), 512, 0, stream>>>(Hbuf, W2t, XgEout,
                                                tile_e, tile_row, numTiles);

  combine_kernel<<<T_TOK, 256, 0, stream>>>(XgEout, tok_slot, tok_w, out);
}